// Round 3
// baseline (781.225 us; speedup 1.0000x reference)
//
#include <hip/hip_runtime.h>

// ---------------------------------------------------------------------------
// B=256, C=2 (ch0 only), T=25, D=4096, H=512, H1=128, NC=2
//  zx = xc @ kernel + bias   (6400 x 2048, K=4096) bf16 MFMA, t-major output
//  LSTM scan T=25: ONE persistent kernel, recF in LDS, c in regs, grid barrier
//  head: softmax(leaky_relu(h@w1+b1) @ w2 + b2)
// ---------------------------------------------------------------------------

typedef __bf16 bf16x8 __attribute__((ext_vector_type(8)));
typedef float  f32x4  __attribute__((ext_vector_type(4)));

#define MFMA16(a, b, c) __builtin_amdgcn_mfma_f32_16x16x32_bf16((a), (b), (c), 0, 0, 0)

__device__ __forceinline__ float sigmf(float x) {
  return 1.0f / (1.0f + __expf(-x));
}
__device__ __forceinline__ float tanhf_(float x) {
  float a = fabsf(x);
  float e = __expf(-2.0f * a);
  float r = (1.0f - e) / (1.0f + e);
  return copysignf(r, x);
}

__device__ __forceinline__ void async16(__bf16* lds, const __bf16* g) {
  __builtin_amdgcn_global_load_lds(
      (const __attribute__((address_space(1))) unsigned int*)g,
      (__attribute__((address_space(3))) unsigned int*)lds, 16, 0, 0);
}

// ---------------------------------------------------------------------------
// x (256,2,25,4096) ch0 -> xb bf16 [6400][4096]
// ---------------------------------------------------------------------------
__global__ __launch_bounds__(256) void conv_xb(const float* __restrict__ x,
                                               __bf16* __restrict__ xb) {
  long o = ((long)blockIdx.x * 256 + threadIdx.x) * 8;
  int m = (int)(o >> 12);
  int k = (int)(o & 4095);
  int b = m / 25, t = m - b * 25;
  const float* src = x + (long)b * 204800 + (long)t * 4096 + k;
  f32x4 v0 = *(const f32x4*)src;
  f32x4 v1 = *(const f32x4*)(src + 4);
  bf16x8 r;
  r[0] = (__bf16)v0[0]; r[1] = (__bf16)v0[1];
  r[2] = (__bf16)v0[2]; r[3] = (__bf16)v0[3];
  r[4] = (__bf16)v1[0]; r[5] = (__bf16)v1[1];
  r[6] = (__bf16)v1[2]; r[7] = (__bf16)v1[3];
  *(bf16x8*)(xb + o) = r;
}

// ---------------------------------------------------------------------------
// kernel (4096,2048) fp32 -> wkT bf16 [2048][4096]
// ---------------------------------------------------------------------------
__global__ __launch_bounds__(256) void conv_wkT(const float* __restrict__ wk,
                                                __bf16* __restrict__ wkT) {
  __shared__ float tile[64][65];
  const int k0 = blockIdx.y * 64;
  const int n0 = blockIdx.x * 64;
  const int tx = threadIdx.x & 63;
  const int ty = threadIdx.x >> 6;
#pragma unroll
  for (int p = 0; p < 16; ++p) {
    int kr = ty + p * 4;
    tile[kr][tx] = wk[(long)(k0 + kr) * 2048 + n0 + tx];
  }
  __syncthreads();
#pragma unroll
  for (int p = 0; p < 16; ++p) {
    int nr = ty + p * 4;
    wkT[(long)(n0 + nr) * 4096 + k0 + tx] = (__bf16)tile[tx][nr];
  }
}

// ---------------------------------------------------------------------------
// rec_kernel (512,2048) fp32 -> recF bf16 fragment order, LDS-tiled.
//   recF[((g*32+jt)*16+ks)*512 + l*8+i] = rec[ks*32+(l>>4)*8+i][g*512+jt*16+(l&15)]
// Block = (g,jt): 128 blocks. tile[512][17] (pad -> ~2-way banks only).
// ---------------------------------------------------------------------------
__global__ __launch_bounds__(256) void conv_recF2(const float* __restrict__ rec,
                                                  __bf16* __restrict__ recF) {
  __shared__ float tile[512][17];
  const int tid = threadIdx.x;
  const int g  = blockIdx.x >> 5;
  const int jt = blockIdx.x & 31;
#pragma unroll 4
  for (int p = 0; p < 32; ++p) {
    int k = (p << 4) + (tid >> 4);
    tile[k][tid & 15] = rec[(long)k * 2048 + (g << 9) + (jt << 4) + (tid & 15)];
  }
  __syncthreads();
  const int l = tid & 63;
  const int w = tid >> 6;
  long obase = ((long)((g * 32 + jt) * 16)) * 512;
#pragma unroll
  for (int q = 0; q < 4; ++q) {
    int ks = (w << 2) + q;
    bf16x8 v;
#pragma unroll
    for (int i = 0; i < 8; ++i)
      v[i] = (__bf16)tile[(ks << 5) + ((l >> 4) << 3) + i][l & 15];
    *(bf16x8*)(recF + obase + (long)ks * 512 + l * 8) = v;
  }
}

// ---------------------------------------------------------------------------
// GEMM (m97 structure + XCD swizzle): zxr[t][b][n] = sum_k xb[m][k]*wkT[n][k]+bias
// ---------------------------------------------------------------------------
__global__ __launch_bounds__(256) void gemm_bf16(const __bf16* __restrict__ A,
                                                 const __bf16* __restrict__ Bt,
                                                 const float* __restrict__ bias,
                                                 float* __restrict__ zxr) {
  __shared__ __bf16 As[128 * 64];
  __shared__ __bf16 Bs[128 * 64];
  const int tid  = threadIdx.x;
  const int wid  = tid >> 6;
  const int lane = tid & 63;

  // XCD-aware swizzle: 800 blocks, 800 % 8 == 0 -> bijective
  const int bid = blockIdx.x;
  const int swz = (bid & 7) * 100 + (bid >> 3);
  const int m0 = (swz >> 4) << 7;   // 50 m-tiles
  const int n0 = (swz & 15) << 7;   // 16 n-tiles

  const int srow  = (wid << 3) + (lane >> 3);
  const int skoff = (lane & 7) << 3;

  const int wr   = (wid >> 1) << 6;
  const int wc   = (wid & 1) << 6;
  const int lrow = lane & 15;
  const int lk8  = (lane >> 4) << 3;

  f32x4 acc[4][4];
#pragma unroll
  for (int i = 0; i < 4; ++i)
#pragma unroll
    for (int jj = 0; jj < 4; ++jj) {
      f32x4 z = {0.f, 0.f, 0.f, 0.f};
      acc[i][jj] = z;
    }

  const __bf16* Ag = A  + (long)(m0 + srow) * 4096 + skoff;
  const __bf16* Bg = Bt + (long)(n0 + srow) * 4096 + skoff;
  __bf16* Al = &As[(wid << 3) * 64];
  __bf16* Bl = &Bs[(wid << 3) * 64];

  for (int k0 = 0; k0 < 4096; k0 += 64) {
    __syncthreads();
#pragma unroll
    for (int q = 0; q < 4; ++q) {
      async16(Al + q * (32 * 64), Ag + (long)(q * 32) * 4096 + k0);
      async16(Bl + q * (32 * 64), Bg + (long)(q * 32) * 4096 + k0);
    }
    __syncthreads();
#pragma unroll
    for (int kk = 0; kk < 2; ++kk) {
      bf16x8 af[4], bv[4];
#pragma unroll
      for (int fr = 0; fr < 4; ++fr)
        af[fr] = *(const bf16x8*)&As[(wr + fr * 16 + lrow) * 64 + (kk << 5) + lk8];
#pragma unroll
      for (int fc = 0; fc < 4; ++fc)
        bv[fc] = *(const bf16x8*)&Bs[(wc + fc * 16 + lrow) * 64 + (kk << 5) + lk8];
#pragma unroll
      for (int fr = 0; fr < 4; ++fr)
#pragma unroll
        for (int fc = 0; fc < 4; ++fc)
          acc[fr][fc] = MFMA16(af[fr], bv[fc], acc[fr][fc]);
    }
  }

  const int mlow = (lane >> 4) << 2;
#pragma unroll
  for (int fc = 0; fc < 4; ++fc) {
    int n = n0 + wc + fc * 16 + lrow;
    float bvs = bias[n];
#pragma unroll
    for (int fr = 0; fr < 4; ++fr) {
      int mb = m0 + wr + fr * 16 + mlow;
#pragma unroll
      for (int r = 0; r < 4; ++r) {
        int m = mb + r;
        int b = m / 25;
        int tt = m - b * 25;
        zxr[((long)((tt << 8) + b) << 11) + n] = acc[fr][fc][r] + bvs;
      }
    }
  }
}

// ---------------------------------------------------------------------------
// Persistent LSTM: 128 blocks x 256 thr (co-resident: 64KB LDS -> 2/CU cap,
// 128 <= 256 CUs). Block=(jt,rtg); wave=(jt, rt). recF slice in LDS once;
// c in registers; h ping-pong global + device-scope epoch barrier.
// zx slab for t+1 prefetched into regs before the barrier.
// ---------------------------------------------------------------------------
__global__ __launch_bounds__(256) void lstm_persist(const float* __restrict__ zxr,
                                                    const __bf16* __restrict__ recF,
                                                    __bf16* __restrict__ hA,
                                                    __bf16* __restrict__ hB,
                                                    __bf16* __restrict__ hplain,
                                                    int* bar) {
  __shared__ __bf16 recS[32768];   // 64 KB: [g][ks][lane][8] for this jt
  const int tid  = threadIdx.x;
  const int wid  = tid >> 6;
  const int lane = tid & 63;
  const int bid  = blockIdx.x;
  const int jt   = bid & 31;
  const int rtg  = bid >> 5;
  const int rt   = (rtg << 2) + wid;

  {
    const __bf16* src = recF + (long)(jt << 4) * 512;   // + g*262144
#pragma unroll
    for (int g = 0; g < 4; ++g)
#pragma unroll
      for (int q = 0; q < 4; ++q)
        *(bf16x8*)(recS + g * 8192 + q * 2048 + tid * 8) =
            *(const bf16x8*)(src + (long)g * 262144 + q * 2048 + tid * 8);
  }

  const int j    = (jt << 4) + (lane & 15);
  const int mlow = (lane >> 4) << 2;
  const int ks2  = j >> 5;
  const int lhi  = ((j >> 3) & 3) << 4;
  const int i2   = j & 7;
  float c[4];
  int brow[4];
#pragma unroll
  for (int r = 0; r < 4; ++r) {
    c[r] = 0.f;
    brow[r] = (rt << 4) + mlow + r;
  }
  __syncthreads();

  float zv[4][4];
#pragma unroll
  for (int g = 0; g < 4; ++g)
#pragma unroll
    for (int r = 0; r < 4; ++r)
      zv[g][r] = zxr[((long)brow[r] << 11) + (g << 9) + j];   // t=0 slab

  const __bf16* hin = hA;
  __bf16* hout = hA;      // t=0 writes hA

  for (int t = 0; t < 25; ++t) {
    if (t > 0) {
      f32x4 acc[4];
#pragma unroll
      for (int g = 0; g < 4; ++g) {
        f32x4 z = {0.f, 0.f, 0.f, 0.f};
        acc[g] = z;
      }
#pragma unroll 4
      for (int ks = 0; ks < 16; ++ks) {
        bf16x8 a = *(const bf16x8*)(hin + ((((rt << 4) + ks) << 6) + lane) * 8);
#pragma unroll
        for (int g = 0; g < 4; ++g) {
          bf16x8 b = *(const bf16x8*)(recS + ((((g << 4) + ks) << 6) + lane) * 8);
          acc[g] = MFMA16(a, b, acc[g]);
        }
      }
#pragma unroll
      for (int g = 0; g < 4; ++g)
#pragma unroll
        for (int r = 0; r < 4; ++r)
          zv[g][r] += acc[g][r];
    }

    // gates + state update (c in registers)
#pragma unroll
    for (int r = 0; r < 4; ++r) {
      float ig = sigmf(zv[0][r]);
      float fg = sigmf(zv[1][r]);
      float gg = tanhf_(zv[2][r]);
      float og = sigmf(zv[3][r]);
      float cn = fg * c[r] + ig * gg;
      c[r] = cn;
      float hv = og * tanhf_(cn);
      hout[((((rt << 4) + ks2) << 6) + (lhi | (brow[r] & 15))) * 8 + i2] = (__bf16)hv;
      if (t == 24) hplain[(brow[r] << 9) + j] = (__bf16)hv;
    }

    if (t < 24) {
      // prefetch next step's zx slab (hides L3 latency under the barrier)
#pragma unroll
      for (int g = 0; g < 4; ++g)
#pragma unroll
        for (int r = 0; r < 4; ++r)
          zv[g][r] = zxr[((long)(((t + 1) << 8) + brow[r]) << 11) + (g << 9) + j];

      // grid barrier, epoch t+1 (monotonic counter; release/acquire, agent scope)
      __syncthreads();
      if (tid == 0) {
        __hip_atomic_fetch_add(bar, 1, __ATOMIC_RELEASE, __HIP_MEMORY_SCOPE_AGENT);
        const int target = 128 * (t + 1);
        while (__hip_atomic_load(bar, __ATOMIC_ACQUIRE, __HIP_MEMORY_SCOPE_AGENT) < target)
          __builtin_amdgcn_s_sleep(2);
      }
      __syncthreads();
    }

    hin  = hout;
    hout = (t & 1) ? hA : hB;   // t=1 writes hB, t=2 hA, ...
  }
}

// ---------------------------------------------------------------------------
// head: y = leaky_relu(h@w1+b1); out = softmax(y@w2+b2). One block per batch.
// ---------------------------------------------------------------------------
__global__ __launch_bounds__(128) void head_kernel(const __bf16* __restrict__ h,
                                                   const float* __restrict__ w1,
                                                   const float* __restrict__ b1,
                                                   const float* __restrict__ w2,
                                                   const float* __restrict__ b2,
                                                   float* __restrict__ out) {
  const int b = blockIdx.x;
  const int j = threadIdx.x;
  float acc = b1[j];
#pragma unroll 8
  for (int k = 0; k < 512; ++k)
    acc += (float)h[b * 512 + k] * w1[k * 128 + j];
  float y = acc > 0.f ? acc : 0.2f * acc;

  __shared__ float s0[128], s1[128];
  s0[j] = y * w2[j * 2 + 0];
  s1[j] = y * w2[j * 2 + 1];
  __syncthreads();
#pragma unroll
  for (int s = 64; s > 0; s >>= 1) {
    if (j < s) { s0[j] += s0[j + s]; s1[j] += s1[j + s]; }
    __syncthreads();
  }
  if (j == 0) {
    float l0 = s0[0] + b2[0];
    float l1 = s1[0] + b2[1];
    float m  = fmaxf(l0, l1);
    float e0 = __expf(l0 - m);
    float e1 = __expf(l1 - m);
    float inv = 1.0f / (e0 + e1);
    out[b * 2 + 0] = e0 * inv;
    out[b * 2 + 1] = e1 * inv;
  }
}

// ---------------------------------------------------------------------------
extern "C" void kernel_launch(void* const* d_in, const int* in_sizes, int n_in,
                              void* d_out, int out_size, void* d_ws, size_t ws_size,
                              hipStream_t stream) {
  const float* x    = (const float*)d_in[0];
  const float* wk   = (const float*)d_in[1];
  const float* rec  = (const float*)d_in[2];
  const float* bias = (const float*)d_in[3];
  const float* w1   = (const float*)d_in[4];
  const float* b1   = (const float*)d_in[5];
  const float* w2   = (const float*)d_in[6];
  const float* b2   = (const float*)d_in[7];
  float* out = (float*)d_out;

  char* w = (char*)d_ws;
  float*  zxr    = (float*)(w + 0);              //  52,428,800  [t][b][2048]
  __bf16* xb     = (__bf16*)(w + 52428800);      //  52,428,800
  __bf16* wkT    = (__bf16*)(w + 104857600);     //  16,777,216
  __bf16* recF   = (__bf16*)(w + 121634816);     //   2,097,152
  __bf16* hA     = (__bf16*)(w + 123731968);     //     262,144
  __bf16* hB     = (__bf16*)(w + 123994112);     //     262,144
  __bf16* hplain = (__bf16*)(w + 124256256);     //     262,144
  int*    bar    = (int*)(w + 124518400);        //         256
                                                 // total 124,518,656

  hipMemsetAsync(bar, 0, 256, stream);

  conv_xb   <<<12800, 256, 0, stream>>>(x, xb);
  conv_wkT  <<<dim3(32, 64), 256, 0, stream>>>(wk, wkT);
  conv_recF2<<<128, 256, 0, stream>>>(rec, recF);

  gemm_bf16<<<800, 256, 0, stream>>>(xb, wkT, bias, zxr);

  lstm_persist<<<128, 256, 0, stream>>>(zxr, recF, hA, hB, hplain, bar);

  head_kernel<<<256, 128, 0, stream>>>(hplain, w1, b1, w2, b2, out);
}

// Round 4
// 736.539 us; speedup vs baseline: 1.0607x; 1.0607x over previous
//
#include <hip/hip_runtime.h>

// ---------------------------------------------------------------------------
// B=256, C=2 (ch0 only), T=25, D=4096, H=512, H1=128, NC=2
//  zx = xc @ kernel + bias   (6400 x 2048, K=4096) bf16 MFMA, b-major output
//  LSTM scan T=25: persistent kernel, 4 independent rtg sync groups (32 blocks
//  each, all-report slot barrier), recF in LDS, c in regs, zx reg-prefetch.
//  head: softmax(leaky_relu(h@w1+b1) @ w2 + b2)
// ---------------------------------------------------------------------------

typedef __bf16 bf16x8 __attribute__((ext_vector_type(8)));
typedef float  f32x4  __attribute__((ext_vector_type(4)));

#define MFMA16(a, b, c) __builtin_amdgcn_mfma_f32_16x16x32_bf16((a), (b), (c), 0, 0, 0)

__device__ __forceinline__ float sigmf(float x) {
  return 1.0f / (1.0f + __expf(-x));
}
__device__ __forceinline__ float tanhf_(float x) {
  float a = fabsf(x);
  float e = __expf(-2.0f * a);
  float r = (1.0f - e) / (1.0f + e);
  return copysignf(r, x);
}

__device__ __forceinline__ void async16(__bf16* lds, const __bf16* g) {
  __builtin_amdgcn_global_load_lds(
      (const __attribute__((address_space(1))) unsigned int*)g,
      (__attribute__((address_space(3))) unsigned int*)lds, 16, 0, 0);
}

// ---------------------------------------------------------------------------
// x (256,2,25,4096) ch0 -> xb bf16 [6400][4096]
// ---------------------------------------------------------------------------
__global__ __launch_bounds__(256) void conv_xb(const float* __restrict__ x,
                                               __bf16* __restrict__ xb) {
  long o = ((long)blockIdx.x * 256 + threadIdx.x) * 8;
  int m = (int)(o >> 12);
  int k = (int)(o & 4095);
  int b = m / 25, t = m - b * 25;
  const float* src = x + (long)b * 204800 + (long)t * 4096 + k;
  f32x4 v0 = *(const f32x4*)src;
  f32x4 v1 = *(const f32x4*)(src + 4);
  bf16x8 r;
  r[0] = (__bf16)v0[0]; r[1] = (__bf16)v0[1];
  r[2] = (__bf16)v0[2]; r[3] = (__bf16)v0[3];
  r[4] = (__bf16)v1[0]; r[5] = (__bf16)v1[1];
  r[6] = (__bf16)v1[2]; r[7] = (__bf16)v1[3];
  *(bf16x8*)(xb + o) = r;
}

// ---------------------------------------------------------------------------
// kernel (4096,2048) fp32 -> wkT bf16 [2048][4096]
// ---------------------------------------------------------------------------
__global__ __launch_bounds__(256) void conv_wkT(const float* __restrict__ wk,
                                                __bf16* __restrict__ wkT) {
  __shared__ float tile[64][65];
  const int k0 = blockIdx.y * 64;
  const int n0 = blockIdx.x * 64;
  const int tx = threadIdx.x & 63;
  const int ty = threadIdx.x >> 6;
#pragma unroll
  for (int p = 0; p < 16; ++p) {
    int kr = ty + p * 4;
    tile[kr][tx] = wk[(long)(k0 + kr) * 2048 + n0 + tx];
  }
  __syncthreads();
#pragma unroll
  for (int p = 0; p < 16; ++p) {
    int nr = ty + p * 4;
    wkT[(long)(n0 + nr) * 4096 + k0 + tx] = (__bf16)tile[tx][nr];
  }
}

// ---------------------------------------------------------------------------
// rec_kernel (512,2048) fp32 -> recF bf16 fragment order, LDS-tiled.
//   recF[((g*32+jt)*16+ks)*512 + l*8+i] = rec[ks*32+(l>>4)*8+i][g*512+jt*16+(l&15)]
// ---------------------------------------------------------------------------
__global__ __launch_bounds__(256) void conv_recF2(const float* __restrict__ rec,
                                                  __bf16* __restrict__ recF) {
  __shared__ float tile[512][17];
  const int tid = threadIdx.x;
  const int g  = blockIdx.x >> 5;
  const int jt = blockIdx.x & 31;
#pragma unroll 4
  for (int p = 0; p < 32; ++p) {
    int k = (p << 4) + (tid >> 4);
    tile[k][tid & 15] = rec[(long)k * 2048 + (g << 9) + (jt << 4) + (tid & 15)];
  }
  __syncthreads();
  const int l = tid & 63;
  const int w = tid >> 6;
  long obase = ((long)((g * 32 + jt) * 16)) * 512;
#pragma unroll
  for (int q = 0; q < 4; ++q) {
    int ks = (w << 2) + q;
    bf16x8 v;
#pragma unroll
    for (int i = 0; i < 8; ++i)
      v[i] = (__bf16)tile[(ks << 5) + ((l >> 4) << 3) + i][l & 15];
    *(bf16x8*)(recF + obase + (long)ks * 512 + l * 8) = v;
  }
}

// ---------------------------------------------------------------------------
// GEMM (m97 structure + XCD swizzle): zx[m][n] = sum_k xb[m][k]*wkT[n][k]+bias
// b-major output: coalesced contiguous row writes.
// ---------------------------------------------------------------------------
__global__ __launch_bounds__(256) void gemm_bf16(const __bf16* __restrict__ A,
                                                 const __bf16* __restrict__ Bt,
                                                 const float* __restrict__ bias,
                                                 float* __restrict__ zx) {
  __shared__ __bf16 As[128 * 64];
  __shared__ __bf16 Bs[128 * 64];
  const int tid  = threadIdx.x;
  const int wid  = tid >> 6;
  const int lane = tid & 63;

  // XCD-aware swizzle: 800 blocks, 800 % 8 == 0 -> bijective
  const int bid = blockIdx.x;
  const int swz = (bid & 7) * 100 + (bid >> 3);
  const int m0 = (swz >> 4) << 7;   // 50 m-tiles
  const int n0 = (swz & 15) << 7;   // 16 n-tiles

  const int srow  = (wid << 3) + (lane >> 3);
  const int skoff = (lane & 7) << 3;

  const int wr   = (wid >> 1) << 6;
  const int wc   = (wid & 1) << 6;
  const int lrow = lane & 15;
  const int lk8  = (lane >> 4) << 3;

  f32x4 acc[4][4];
#pragma unroll
  for (int i = 0; i < 4; ++i)
#pragma unroll
    for (int jj = 0; jj < 4; ++jj) {
      f32x4 z = {0.f, 0.f, 0.f, 0.f};
      acc[i][jj] = z;
    }

  const __bf16* Ag = A  + (long)(m0 + srow) * 4096 + skoff;
  const __bf16* Bg = Bt + (long)(n0 + srow) * 4096 + skoff;
  __bf16* Al = &As[(wid << 3) * 64];
  __bf16* Bl = &Bs[(wid << 3) * 64];

  for (int k0 = 0; k0 < 4096; k0 += 64) {
    __syncthreads();
#pragma unroll
    for (int q = 0; q < 4; ++q) {
      async16(Al + q * (32 * 64), Ag + (long)(q * 32) * 4096 + k0);
      async16(Bl + q * (32 * 64), Bg + (long)(q * 32) * 4096 + k0);
    }
    __syncthreads();
#pragma unroll
    for (int kk = 0; kk < 2; ++kk) {
      bf16x8 af[4], bv[4];
#pragma unroll
      for (int fr = 0; fr < 4; ++fr)
        af[fr] = *(const bf16x8*)&As[(wr + fr * 16 + lrow) * 64 + (kk << 5) + lk8];
#pragma unroll
      for (int fc = 0; fc < 4; ++fc)
        bv[fc] = *(const bf16x8*)&Bs[(wc + fc * 16 + lrow) * 64 + (kk << 5) + lk8];
#pragma unroll
      for (int fr = 0; fr < 4; ++fr)
#pragma unroll
        for (int fc = 0; fc < 4; ++fc)
          acc[fr][fc] = MFMA16(af[fr], bv[fc], acc[fr][fc]);
    }
  }

  const int mlow = (lane >> 4) << 2;
#pragma unroll
  for (int fc = 0; fc < 4; ++fc) {
    int n = n0 + wc + fc * 16 + lrow;
    float bvs = bias[n];
#pragma unroll
    for (int fr = 0; fr < 4; ++fr) {
      int mb = m0 + wr + fr * 16 + mlow;
#pragma unroll
      for (int r = 0; r < 4; ++r)
        zx[(long)(mb + r) * 2048 + n] = acc[fr][fc][r] + bvs;
    }
  }
}

// ---------------------------------------------------------------------------
// Persistent LSTM: 128 blocks x 256 thr. Block=(jt, rtg); 4 independent sync
// groups by rtg (32 blocks each; a group only exchanges h rows of its rtg).
// All-report barrier: release-store own slot, 32 lanes acquire-poll peers.
// recF slice in LDS once; c in regs; zx (b-major) prefetched pre-barrier.
// ---------------------------------------------------------------------------
__global__ __launch_bounds__(256) void lstm_persist(const float* __restrict__ zx,
                                                    const __bf16* __restrict__ recF,
                                                    __bf16* __restrict__ hA,
                                                    __bf16* __restrict__ hB,
                                                    __bf16* __restrict__ hplain,
                                                    int* bar) {
  __shared__ __bf16 recS[32768];   // 64 KB: [g][ks][lane][8] for this jt
  const int tid  = threadIdx.x;
  const int wid  = tid >> 6;
  const int lane = tid & 63;
  const int bid  = blockIdx.x;
  const int jt   = bid & 31;
  const int rtg  = bid >> 5;
  const int rt   = (rtg << 2) + wid;
  int* gbar = bar + (rtg << 6);    // group slots: 32 ints (256B-padded groups)

  {
    const __bf16* src = recF + (long)(jt << 4) * 512;   // + g*262144
#pragma unroll
    for (int g = 0; g < 4; ++g)
#pragma unroll
      for (int q = 0; q < 4; ++q)
        *(bf16x8*)(recS + g * 8192 + q * 2048 + tid * 8) =
            *(const bf16x8*)(src + (long)g * 262144 + q * 2048 + tid * 8);
  }

  const int j    = (jt << 4) + (lane & 15);
  const int mlow = (lane >> 4) << 2;
  const int ks2  = j >> 5;
  const int lhi  = ((j >> 3) & 3) << 4;
  const int i2   = j & 7;
  float c[4];
  int brow[4];
#pragma unroll
  for (int r = 0; r < 4; ++r) {
    c[r] = 0.f;
    brow[r] = (rt << 4) + mlow + r;
  }
  __syncthreads();

  float zv[4][4];
#pragma unroll
  for (int g = 0; g < 4; ++g)
#pragma unroll
    for (int r = 0; r < 4; ++r)
      zv[g][r] = zx[(((long)brow[r] * 25) << 11) + (g << 9) + j];   // t=0 slab

  const __bf16* hin = hA;
  __bf16* hout = hA;      // t=0 writes hA

  for (int t = 0; t < 25; ++t) {
    if (t > 0) {
      f32x4 acc[4];
#pragma unroll
      for (int g = 0; g < 4; ++g) {
        f32x4 z = {0.f, 0.f, 0.f, 0.f};
        acc[g] = z;
      }
#pragma unroll 4
      for (int ks = 0; ks < 16; ++ks) {
        bf16x8 a = *(const bf16x8*)(hin + ((((rt << 4) + ks) << 6) + lane) * 8);
#pragma unroll
        for (int g = 0; g < 4; ++g) {
          bf16x8 b = *(const bf16x8*)(recS + ((((g << 4) + ks) << 6) + lane) * 8);
          acc[g] = MFMA16(a, b, acc[g]);
        }
      }
#pragma unroll
      for (int g = 0; g < 4; ++g)
#pragma unroll
        for (int r = 0; r < 4; ++r)
          zv[g][r] += acc[g][r];
    }

    // gates + state update (c in registers)
#pragma unroll
    for (int r = 0; r < 4; ++r) {
      float ig = sigmf(zv[0][r]);
      float fg = sigmf(zv[1][r]);
      float gg = tanhf_(zv[2][r]);
      float og = sigmf(zv[3][r]);
      float cn = fg * c[r] + ig * gg;
      c[r] = cn;
      float hv = og * tanhf_(cn);
      hout[((((rt << 4) + ks2) << 6) + (lhi | (brow[r] & 15))) * 8 + i2] = (__bf16)hv;
      if (t == 24) hplain[(brow[r] << 9) + j] = (__bf16)hv;
    }

    if (t < 24) {
      // prefetch next step's zx slab into regs (hides latency under the spin)
#pragma unroll
      for (int g = 0; g < 4; ++g)
#pragma unroll
        for (int r = 0; r < 4; ++r)
          zv[g][r] = zx[(((long)brow[r] * 25 + t + 1) << 11) + (g << 9) + j];

      // group barrier: release own slot, 32 lanes acquire-poll all peers
      __syncthreads();
      if (tid == 0)
        __hip_atomic_store(&gbar[jt], t + 1, __ATOMIC_RELEASE,
                           __HIP_MEMORY_SCOPE_AGENT);
      if (tid < 32) {
        while (__hip_atomic_load(&gbar[tid], __ATOMIC_ACQUIRE,
                                 __HIP_MEMORY_SCOPE_AGENT) < t + 1)
          __builtin_amdgcn_s_sleep(4);
      }
      __syncthreads();
    }

    hin  = hout;
    hout = (t & 1) ? hA : hB;   // t=1 writes hB, t=2 hA, ...
  }
}

// ---------------------------------------------------------------------------
// head: y = leaky_relu(h@w1+b1); out = softmax(y@w2+b2). One block per batch.
// ---------------------------------------------------------------------------
__global__ __launch_bounds__(128) void head_kernel(const __bf16* __restrict__ h,
                                                   const float* __restrict__ w1,
                                                   const float* __restrict__ b1,
                                                   const float* __restrict__ w2,
                                                   const float* __restrict__ b2,
                                                   float* __restrict__ out) {
  const int b = blockIdx.x;
  const int j = threadIdx.x;
  float acc = b1[j];
#pragma unroll 8
  for (int k = 0; k < 512; ++k)
    acc += (float)h[b * 512 + k] * w1[k * 128 + j];
  float y = acc > 0.f ? acc : 0.2f * acc;

  __shared__ float s0[128], s1[128];
  s0[j] = y * w2[j * 2 + 0];
  s1[j] = y * w2[j * 2 + 1];
  __syncthreads();
#pragma unroll
  for (int s = 64; s > 0; s >>= 1) {
    if (j < s) { s0[j] += s0[j + s]; s1[j] += s1[j + s]; }
    __syncthreads();
  }
  if (j == 0) {
    float l0 = s0[0] + b2[0];
    float l1 = s1[0] + b2[1];
    float m  = fmaxf(l0, l1);
    float e0 = __expf(l0 - m);
    float e1 = __expf(l1 - m);
    float inv = 1.0f / (e0 + e1);
    out[b * 2 + 0] = e0 * inv;
    out[b * 2 + 1] = e1 * inv;
  }
}

// ---------------------------------------------------------------------------
extern "C" void kernel_launch(void* const* d_in, const int* in_sizes, int n_in,
                              void* d_out, int out_size, void* d_ws, size_t ws_size,
                              hipStream_t stream) {
  const float* x    = (const float*)d_in[0];
  const float* wk   = (const float*)d_in[1];
  const float* rec  = (const float*)d_in[2];
  const float* bias = (const float*)d_in[3];
  const float* w1   = (const float*)d_in[4];
  const float* b1   = (const float*)d_in[5];
  const float* w2   = (const float*)d_in[6];
  const float* b2   = (const float*)d_in[7];
  float* out = (float*)d_out;

  char* w = (char*)d_ws;
  float*  zx     = (float*)(w + 0);              //  52,428,800  [b*25+t][2048]
  __bf16* xb     = (__bf16*)(w + 52428800);      //  52,428,800
  __bf16* wkT    = (__bf16*)(w + 104857600);     //  16,777,216
  __bf16* recF   = (__bf16*)(w + 121634816);     //   2,097,152
  __bf16* hA     = (__bf16*)(w + 123731968);     //     262,144
  __bf16* hB     = (__bf16*)(w + 123994112);     //     262,144
  __bf16* hplain = (__bf16*)(w + 124256256);     //     262,144
  int*    bar    = (int*)(w + 124518400);        //       1,024
                                                 // total 124,519,424

  hipMemsetAsync(bar, 0, 1024, stream);

  conv_xb   <<<12800, 256, 0, stream>>>(x, xb);
  conv_wkT  <<<dim3(32, 64), 256, 0, stream>>>(wk, wkT);
  conv_recF2<<<128, 256, 0, stream>>>(rec, recF);

  gemm_bf16<<<800, 256, 0, stream>>>(xb, wkT, bias, zx);

  lstm_persist<<<128, 256, 0, stream>>>(zx, recF, hA, hB, hplain, bar);

  head_kernel<<<256, 128, 0, stream>>>(hplain, w1, b1, w2, b2, out);
}

// Round 5
// 705.368 us; speedup vs baseline: 1.1075x; 1.0442x over previous
//
#include <hip/hip_runtime.h>

// ---------------------------------------------------------------------------
// B=256, C=2 (ch0 only), T=25, D=4096, H=512, H1=128, NC=2
//  zx = xc @ kernel + bias   (6400 x 2048, K=4096) bf16 MFMA (m97-style)
//  LSTM scan T=25: persistent kernel, 8 XCD-local sync groups of 16 blocks
//  (bid&7 keyed -> co-XCD under round-robin dispatch; correctness is
//  placement-independent). Block = 32 rows x 32 cols x 4 gates, 128KB LDS rec
//  slice, c in regs, relaxed-poll barrier + single acquire, zx reg-prefetch.
//  head: softmax(leaky_relu(h@w1+b1) @ w2 + b2)
// ---------------------------------------------------------------------------

typedef __bf16 bf16x8 __attribute__((ext_vector_type(8)));
typedef float  f32x4  __attribute__((ext_vector_type(4)));

#define MFMA16(a, b, c) __builtin_amdgcn_mfma_f32_16x16x32_bf16((a), (b), (c), 0, 0, 0)

__device__ __forceinline__ float sigmf(float x) {
  return 1.0f / (1.0f + __expf(-x));
}
__device__ __forceinline__ float tanhf_(float x) {
  float a = fabsf(x);
  float e = __expf(-2.0f * a);
  float r = (1.0f - e) / (1.0f + e);
  return copysignf(r, x);
}

__device__ __forceinline__ void async16(__bf16* lds, const __bf16* g) {
  __builtin_amdgcn_global_load_lds(
      (const __attribute__((address_space(1))) unsigned int*)g,
      (__attribute__((address_space(3))) unsigned int*)lds, 16, 0, 0);
}

// ---------------------------------------------------------------------------
// x (256,2,25,4096) ch0 -> xb bf16 [6400][4096]
// ---------------------------------------------------------------------------
__global__ __launch_bounds__(256) void conv_xb(const float* __restrict__ x,
                                               __bf16* __restrict__ xb) {
  long o = ((long)blockIdx.x * 256 + threadIdx.x) * 8;
  int m = (int)(o >> 12);
  int k = (int)(o & 4095);
  int b = m / 25, t = m - b * 25;
  const float* src = x + (long)b * 204800 + (long)t * 4096 + k;
  f32x4 v0 = *(const f32x4*)src;
  f32x4 v1 = *(const f32x4*)(src + 4);
  bf16x8 r;
  r[0] = (__bf16)v0[0]; r[1] = (__bf16)v0[1];
  r[2] = (__bf16)v0[2]; r[3] = (__bf16)v0[3];
  r[4] = (__bf16)v1[0]; r[5] = (__bf16)v1[1];
  r[6] = (__bf16)v1[2]; r[7] = (__bf16)v1[3];
  *(bf16x8*)(xb + o) = r;
}

// ---------------------------------------------------------------------------
// kernel (4096,2048) fp32 -> wkT bf16 [2048][4096]
// ---------------------------------------------------------------------------
__global__ __launch_bounds__(256) void conv_wkT(const float* __restrict__ wk,
                                                __bf16* __restrict__ wkT) {
  __shared__ float tile[64][65];
  const int k0 = blockIdx.y * 64;
  const int n0 = blockIdx.x * 64;
  const int tx = threadIdx.x & 63;
  const int ty = threadIdx.x >> 6;
#pragma unroll
  for (int p = 0; p < 16; ++p) {
    int kr = ty + p * 4;
    tile[kr][tx] = wk[(long)(k0 + kr) * 2048 + n0 + tx];
  }
  __syncthreads();
#pragma unroll
  for (int p = 0; p < 16; ++p) {
    int nr = ty + p * 4;
    wkT[(long)(n0 + nr) * 4096 + k0 + tx] = (__bf16)tile[tx][nr];
  }
}

// ---------------------------------------------------------------------------
// rec_kernel (512,2048) fp32 -> recF bf16 fragment order, LDS-tiled.
//   recF[((g*32+jt)*16+ks)*512 + l*8+i] = rec[ks*32+(l>>4)*8+i][g*512+jt*16+(l&15)]
// ---------------------------------------------------------------------------
__global__ __launch_bounds__(256) void conv_recF2(const float* __restrict__ rec,
                                                  __bf16* __restrict__ recF) {
  __shared__ float tile[512][17];
  const int tid = threadIdx.x;
  const int g  = blockIdx.x >> 5;
  const int jt = blockIdx.x & 31;
#pragma unroll 4
  for (int p = 0; p < 32; ++p) {
    int k = (p << 4) + (tid >> 4);
    tile[k][tid & 15] = rec[(long)k * 2048 + (g << 9) + (jt << 4) + (tid & 15)];
  }
  __syncthreads();
  const int l = tid & 63;
  const int w = tid >> 6;
  long obase = ((long)((g * 32 + jt) * 16)) * 512;
#pragma unroll
  for (int q = 0; q < 4; ++q) {
    int ks = (w << 2) + q;
    bf16x8 v;
#pragma unroll
    for (int i = 0; i < 8; ++i)
      v[i] = (__bf16)tile[(ks << 5) + ((l >> 4) << 3) + i][l & 15];
    *(bf16x8*)(recF + obase + (long)ks * 512 + l * 8) = v;
  }
}

// ---------------------------------------------------------------------------
// GEMM (m97 structure, dim3(16,50) grid -- XCD gets 2 n-columns, B L2-resident)
// zx[m][n] = sum_k xb[m][k]*wkT[n][k] + bias[n], b-major coalesced writes.
// ---------------------------------------------------------------------------
__global__ __launch_bounds__(256) void gemm_bf16(const __bf16* __restrict__ A,
                                                 const __bf16* __restrict__ Bt,
                                                 const float* __restrict__ bias,
                                                 float* __restrict__ zx) {
  __shared__ __bf16 As[128 * 64];
  __shared__ __bf16 Bs[128 * 64];
  const int tid  = threadIdx.x;
  const int wid  = tid >> 6;
  const int lane = tid & 63;
  const int m0 = blockIdx.y * 128;
  const int n0 = blockIdx.x * 128;

  const int srow  = (wid << 3) + (lane >> 3);
  const int skoff = (lane & 7) << 3;

  const int wr   = (wid >> 1) << 6;
  const int wc   = (wid & 1) << 6;
  const int lrow = lane & 15;
  const int lk8  = (lane >> 4) << 3;

  f32x4 acc[4][4];
#pragma unroll
  for (int i = 0; i < 4; ++i)
#pragma unroll
    for (int jj = 0; jj < 4; ++jj) {
      f32x4 z = {0.f, 0.f, 0.f, 0.f};
      acc[i][jj] = z;
    }

  const __bf16* Ag = A  + (long)(m0 + srow) * 4096 + skoff;
  const __bf16* Bg = Bt + (long)(n0 + srow) * 4096 + skoff;
  __bf16* Al = &As[(wid << 3) * 64];
  __bf16* Bl = &Bs[(wid << 3) * 64];

  for (int k0 = 0; k0 < 4096; k0 += 64) {
    __syncthreads();
#pragma unroll
    for (int q = 0; q < 4; ++q) {
      async16(Al + q * (32 * 64), Ag + (long)(q * 32) * 4096 + k0);
      async16(Bl + q * (32 * 64), Bg + (long)(q * 32) * 4096 + k0);
    }
    __syncthreads();
#pragma unroll
    for (int kk = 0; kk < 2; ++kk) {
      bf16x8 af[4], bv[4];
#pragma unroll
      for (int fr = 0; fr < 4; ++fr)
        af[fr] = *(const bf16x8*)&As[(wr + fr * 16 + lrow) * 64 + (kk << 5) + lk8];
#pragma unroll
      for (int fc = 0; fc < 4; ++fc)
        bv[fc] = *(const bf16x8*)&Bs[(wc + fc * 16 + lrow) * 64 + (kk << 5) + lk8];
#pragma unroll
      for (int fr = 0; fr < 4; ++fr)
#pragma unroll
        for (int fc = 0; fc < 4; ++fc)
          acc[fr][fc] = MFMA16(af[fr], bv[fc], acc[fr][fc]);
    }
  }

  const int mlow = (lane >> 4) << 2;
#pragma unroll
  for (int fc = 0; fc < 4; ++fc) {
    int n = n0 + wc + fc * 16 + lrow;
    float bvs = bias[n];
#pragma unroll
    for (int fr = 0; fr < 4; ++fr) {
      int mb = m0 + wr + fr * 16 + mlow;
#pragma unroll
      for (int r = 0; r < 4; ++r)
        zx[(long)(mb + r) * 2048 + n] = acc[fr][fc][r] + bvs;
    }
  }
}

// ---------------------------------------------------------------------------
// Persistent LSTM: 128 blocks x 256 thr, 128KB LDS (1 block/CU).
// Group = bid&7 (8 groups of 16 blocks; co-XCD under round-robin dispatch).
// Group owns rows g8*32..+32; block jb=bid>>3 owns cols jb*32..+32, all gates.
// Wave (rt=wid>>1, jt2=wid&1): 16 rows x 16 cols x 4 gates.
// hF layout: [rtile(16)][ks(16)][lane(64)][8]; block writes ks==jb only.
// ---------------------------------------------------------------------------
__global__ __launch_bounds__(256) void lstm_persist(const float* __restrict__ zx,
                                                    const __bf16* __restrict__ recF,
                                                    __bf16* __restrict__ hA,
                                                    __bf16* __restrict__ hB,
                                                    __bf16* __restrict__ hplain,
                                                    int* bar) {
  __shared__ __bf16 recS[65536];   // 128 KB: [g(4)][jt2(2)][ks(16)][lane][8]
  const int tid  = threadIdx.x;
  const int wid  = tid >> 6;
  const int lane = tid & 63;
  const int bid  = blockIdx.x;
  const int g8   = bid & 7;        // sync group / XCD
  const int jb   = bid >> 3;       // member 0..15, owns cols [jb*32, jb*32+32)
  const int rt   = wid >> 1;       // row tile within group (0..1)
  const int jt2  = wid & 1;        // col half (0..1)
  const int rtile = (g8 << 1) + rt;
  int* gbar = bar + (g8 << 6);     // 16 slots per group (256B padded)

  // stage recF slice -> LDS: gates 0..3 x jt in {2jb, 2jb+1}, 8192 elems each
  {
#pragma unroll
    for (int g = 0; g < 4; ++g)
#pragma unroll
      for (int c2 = 0; c2 < 2; ++c2) {
        const __bf16* src = recF + ((long)(g * 32 + (jb << 1) + c2) << 13);
        __bf16* dst = recS + (((g << 1) + c2) << 13);
#pragma unroll
        for (int q = 0; q < 4; ++q)
          *(bf16x8*)(dst + (q << 11) + tid * 8) =
              *(const bf16x8*)(src + (q << 11) + tid * 8);
      }
  }

  const int lrow = lane & 15;
  const int lhi4 = lane >> 4;
  const int j    = (jb << 5) + (jt2 << 4) + lrow;      // this thread's h col
  const int khi  = (j >> 3) & 3;
  const int i2   = j & 7;
  float c[4];
  int brow[4];
#pragma unroll
  for (int r = 0; r < 4; ++r) {
    c[r] = 0.f;
    brow[r] = (g8 << 5) + (rt << 4) + (lhi4 << 2) + r;
  }
  __syncthreads();

  float zv[4][4];
#pragma unroll
  for (int g = 0; g < 4; ++g)
#pragma unroll
    for (int r = 0; r < 4; ++r)
      zv[g][r] = zx[(((long)brow[r] * 25) << 11) + (g << 9) + j];   // t=0

  const __bf16* hin = hA;
  __bf16* hout = hA;      // t=0 writes hA

  for (int t = 0; t < 25; ++t) {
    if (t > 0) {
      f32x4 acc[4];
#pragma unroll
      for (int g = 0; g < 4; ++g) {
        f32x4 z = {0.f, 0.f, 0.f, 0.f};
        acc[g] = z;
      }
#pragma unroll 4
      for (int ks = 0; ks < 16; ++ks) {
        bf16x8 a = *(const bf16x8*)(hin + ((((rtile << 4) + ks) << 6) + lane) * 8);
#pragma unroll
        for (int g = 0; g < 4; ++g) {
          bf16x8 b = *(const bf16x8*)(recS +
              (((((g << 1) + jt2) << 4) + ks) << 9) + lane * 8);
          acc[g] = MFMA16(a, b, acc[g]);
        }
      }
#pragma unroll
      for (int g = 0; g < 4; ++g)
#pragma unroll
        for (int r = 0; r < 4; ++r)
          zv[g][r] += acc[g][r];
    }

    // gates + state update (c in registers); write h fragment (ks == jb)
#pragma unroll
    for (int r = 0; r < 4; ++r) {
      float ig = sigmf(zv[0][r]);
      float fg = sigmf(zv[1][r]);
      float gg = tanhf_(zv[2][r]);
      float og = sigmf(zv[3][r]);
      float cn = fg * c[r] + ig * gg;
      c[r] = cn;
      float hv = og * tanhf_(cn);
      int lane_w = (khi << 4) | (lhi4 << 2) | r;
      hout[((((rtile << 4) + jb) << 6) + lane_w) * 8 + i2] = (__bf16)hv;
      if (t == 24) hplain[(brow[r] << 9) + j] = (__bf16)hv;
    }

    if (t < 24) {
      __syncthreads();   // all h stores in this block retired (barrier drains)
      if (tid == 0)
        __hip_atomic_store(&gbar[jb], t + 1, __ATOMIC_RELEASE,
                           __HIP_MEMORY_SCOPE_AGENT);

      // prefetch next step's zx slab while waiting (overlaps peer wait)
#pragma unroll
      for (int g = 0; g < 4; ++g)
#pragma unroll
        for (int r = 0; r < 4; ++r)
          zv[g][r] = zx[(((long)brow[r] * 25 + t + 1) << 11) + (g << 9) + j];

      // relaxed poll (no per-iteration cache inv), single acquire at exit
      if (tid < 16) {
        while (__hip_atomic_load(&gbar[tid], __ATOMIC_RELAXED,
                                 __HIP_MEMORY_SCOPE_AGENT) < t + 1)
          __builtin_amdgcn_s_sleep(2);
        (void)__hip_atomic_load(&gbar[tid], __ATOMIC_ACQUIRE,
                                __HIP_MEMORY_SCOPE_AGENT);
      }
      __syncthreads();
    }

    hin  = hout;
    hout = (t & 1) ? hA : hB;   // t=1 writes hB, t=2 hA, ...
  }
}

// ---------------------------------------------------------------------------
// head: y = leaky_relu(h@w1+b1); out = softmax(y@w2+b2). One block per batch.
// ---------------------------------------------------------------------------
__global__ __launch_bounds__(128) void head_kernel(const __bf16* __restrict__ h,
                                                   const float* __restrict__ w1,
                                                   const float* __restrict__ b1,
                                                   const float* __restrict__ w2,
                                                   const float* __restrict__ b2,
                                                   float* __restrict__ out) {
  const int b = blockIdx.x;
  const int j = threadIdx.x;
  float acc = b1[j];
#pragma unroll 8
  for (int k = 0; k < 512; ++k)
    acc += (float)h[b * 512 + k] * w1[k * 128 + j];
  float y = acc > 0.f ? acc : 0.2f * acc;

  __shared__ float s0[128], s1[128];
  s0[j] = y * w2[j * 2 + 0];
  s1[j] = y * w2[j * 2 + 1];
  __syncthreads();
#pragma unroll
  for (int s = 64; s > 0; s >>= 1) {
    if (j < s) { s0[j] += s0[j + s]; s1[j] += s1[j + s]; }
    __syncthreads();
  }
  if (j == 0) {
    float l0 = s0[0] + b2[0];
    float l1 = s1[0] + b2[1];
    float m  = fmaxf(l0, l1);
    float e0 = __expf(l0 - m);
    float e1 = __expf(l1 - m);
    float inv = 1.0f / (e0 + e1);
    out[b * 2 + 0] = e0 * inv;
    out[b * 2 + 1] = e1 * inv;
  }
}

// ---------------------------------------------------------------------------
extern "C" void kernel_launch(void* const* d_in, const int* in_sizes, int n_in,
                              void* d_out, int out_size, void* d_ws, size_t ws_size,
                              hipStream_t stream) {
  const float* x    = (const float*)d_in[0];
  const float* wk   = (const float*)d_in[1];
  const float* rec  = (const float*)d_in[2];
  const float* bias = (const float*)d_in[3];
  const float* w1   = (const float*)d_in[4];
  const float* b1   = (const float*)d_in[5];
  const float* w2   = (const float*)d_in[6];
  const float* b2   = (const float*)d_in[7];
  float* out = (float*)d_out;

  char* w = (char*)d_ws;
  float*  zx     = (float*)(w + 0);              //  52,428,800  [b*25+t][2048]
  __bf16* xb     = (__bf16*)(w + 52428800);      //  52,428,800
  __bf16* wkT    = (__bf16*)(w + 104857600);     //  16,777,216
  __bf16* recF   = (__bf16*)(w + 121634816);     //   2,097,152
  __bf16* hA     = (__bf16*)(w + 123731968);     //     262,144
  __bf16* hB     = (__bf16*)(w + 123994112);     //     262,144
  __bf16* hplain = (__bf16*)(w + 124256256);     //     262,144
  int*    bar    = (int*)(w + 124518400);        //       2,048
                                                 // total 124,520,448

  hipMemsetAsync(bar, 0, 2048, stream);

  conv_xb   <<<12800, 256, 0, stream>>>(x, xb);
  conv_wkT  <<<dim3(32, 64), 256, 0, stream>>>(wk, wkT);
  conv_recF2<<<128, 256, 0, stream>>>(rec, recF);

  gemm_bf16<<<dim3(16, 50), 256, 0, stream>>>(xb, wkT, bias, zx);

  lstm_persist<<<128, 256, 0, stream>>>(zx, recF, hA, hB, hplain, bar);

  head_kernel<<<256, 128, 0, stream>>>(hplain, w1, b1, w2, b2, out);
}